// Round 1
// baseline (38251.208 us; speedup 1.0000x reference)
//
#include <hip/hip_runtime.h>
#include <math.h>

typedef __bf16 bf16;
typedef __bf16 bf16x8 __attribute__((ext_vector_type(8)));
typedef float f32x4 __attribute__((ext_vector_type(4)));
typedef unsigned int u32;

#define TT 1024
#define BB 32
#define DD 512
#define HH 512
#define NG4 2048

// workspace layout (bytes)
#define OFF_FLAGS 0ull
#define OFF_WBT   32768ull
#define OFF_H0    (OFF_WBT + 2097152ull)
#define RING      16
#define RING_ELEM ((size_t)RING*BB*HH)              // floats per layer-0 ring
#define OFF_H1    (OFF_H0 + 2ull*RING_ELEM*4ull)
#define FULL_ELEM ((size_t)(TT+1)*BB*HH)            // floats per layer-1 buffer

__device__ __forceinline__ bool spinf(int* p, int* abortf) {
  int it = 0;
  while (__hip_atomic_load(p, __ATOMIC_RELAXED, __HIP_MEMORY_SCOPE_AGENT) < 64) {
    __builtin_amdgcn_s_sleep(1);
    if (++it > (1 << 23)) {
      __hip_atomic_store(abortf, 1, __ATOMIC_RELAXED, __HIP_MEMORY_SCOPE_AGENT);
      return false;
    }
    if ((it & 2047) == 0 &&
        __hip_atomic_load(abortf, __ATOMIC_RELAXED, __HIP_MEMORY_SCOPE_AGENT))
      return false;
  }
  (void)__hip_atomic_load(p, __ATOMIC_ACQUIRE, __HIP_MEMORY_SCOPE_AGENT);
  return true;
}

__global__ void k_setup(const float* __restrict__ h0,
                        const float* __restrict__ wout,
                        unsigned char* __restrict__ ws) {
  bf16* wbt   = (bf16*)(ws + OFF_WBT);
  float* h0r  = (float*)(ws + OFF_H0);
  float* h1r  = (float*)(ws + OFF_H1);
  int* flags  = (int*)(ws + OFF_FLAGS);
  const u32 wcnt = 1024u*1024u;
  const u32 icnt = 4u*BB*HH;
  const u32 fcnt = 4u*1024u + 4u;
  const u32 total = wcnt + icnt + fcnt;
  for (u32 i = blockIdx.x*blockDim.x + threadIdx.x; i < total; i += gridDim.x*blockDim.x) {
    if (i < wcnt) {
      u32 j = i >> 10, k = i & 1023u;
      wbt[(size_t)j*1024u + k] = (bf16)wout[(size_t)k*1024u + j]; // transpose W_out
    } else if (i < wcnt + icnt) {
      u32 t = i - wcnt;
      u32 g = t >> 14;          // (layer*2+dir)
      u32 rem = t & 16383u;     // b*512+k
      u32 l = g >> 1;
      float v = h0[(size_t)l*(BB*HH) + rem];
      if (g < 2) h0r[(size_t)g*RING_ELEM + rem] = v;
      else       h1r[(size_t)(g-2)*FULL_ELEM + rem] = v;
    } else {
      flags[i - wcnt - icnt] = 0;
    }
  }
}

// swizzles: rows are 1024B (rnn) / 128B (gemm); XOR bits 4-6 by row kills bank conflicts
#define SWZ(row, bc)  ((u32)(row)*1024u + ((u32)(bc) ^ ((((u32)(row))&7u)<<4)))
#define SWZG(row, bc) ((u32)(row)*128u  + ((u32)(bc) ^ ((((u32)(row))&7u)<<4)))

__launch_bounds__(256, 1)
__global__ void k_rnn(const float* __restrict__ x,
                      const float* __restrict__ c0,
                      const float* __restrict__ Wi_f, const float* __restrict__ Wh_f, const float* __restrict__ b_f,
                      const float* __restrict__ Wi_b, const float* __restrict__ Wh_b, const float* __restrict__ b_b,
                      unsigned char* __restrict__ ws) {
  __shared__ unsigned char sXs[32*1024];    // X tile bf16 [32][512] swizzled
  __shared__ unsigned char sHhi[32*1024];   // h hi
  __shared__ unsigned char sHlo[32*1024];   // h lo
  __shared__ unsigned char sWhlo[32*1024];  // Wh lo fragments [nt][ks][lane*16B]
  __shared__ float gatebuf[32*32];
  __shared__ int sab;

  const int bid = blockIdx.x;
  const int g = bid & 3;            // (layer*2 + dir); spreads groups across XCDs
  const int w = bid >> 2;           // 0..63 within group: owns hidden units w*8..w*8+7
  const int l = g >> 1, d = g & 1;
  const int tid = threadIdx.x;
  const int lane = tid & 63;
  const int q = tid >> 6;           // wave 0..3
  const int mt = q >> 1, nt = q & 1;

  const float* Wi   = (d ? Wi_b : Wi_f) + (size_t)l*DD*NG4;
  const float* Wh   = (d ? Wh_b : Wh_f) + (size_t)l*HH*NG4;
  const float* bias = (d ? b_b : b_f) + (size_t)l*NG4;

  float* H0r = (float*)(ws + OFF_H0);
  float* H1r = (float*)(ws + OFF_H1);
  float* Hown = (l == 0) ? (H0r + (size_t)d*RING_ELEM) : (H1r + (size_t)d*FULL_ELEM);
  float* Hin  = H0r + (size_t)d*RING_ELEM;      // layer-1 input
  int* flags  = (int*)(ws + OFF_FLAGS);
  int* abortf = flags + 4096;

  // ---- one-time: pack weight B-fragments into registers (Wh lo -> LDS) ----
  // wg column c = unit*4 + gate; global gate col J = gate*512 + w*8 + unit
  const int c_loc = nt*16 + (lane & 15);
  const int unit = c_loc >> 2, gate = c_loc & 3;
  const int Jcol = gate*512 + w*8 + unit;
  const int kr0 = (lane >> 4) * 8;

  bf16x8 BWi[16], BWh[16];
#pragma unroll
  for (int ks = 0; ks < 16; ++ks) {
    int k0 = ks*32 + kr0;
    bf16x8 ai, ah, alo;
#pragma unroll
    for (int e = 0; e < 8; ++e) {
      float wi = Wi[(size_t)(k0+e)*NG4 + Jcol];
      float wh = Wh[(size_t)(k0+e)*NG4 + Jcol];
      ai[e] = (bf16)wi;
      bf16 hh = (bf16)wh;
      ah[e] = hh;
      alo[e] = (bf16)(wh - (float)hh);
    }
    BWi[ks] = ai; BWh[ks] = ah;
    if (mt == 0)
      *(bf16x8*)(sWhlo + (u32)nt*16384u + (u32)ks*1024u + (u32)lane*16u) = alo;
  }

  const int bthr = tid >> 3, uthr = tid & 7;
  const int hu = w*8 + uthr;
  float cst = c0[((size_t)l*BB + bthr)*HH + hu];
  const float bgi = bias[hu], bgf = bias[512+hu], bgg = bias[1024+hu], bgo = bias[1536+hu];

  if (tid == 0) sab = 0;
  __syncthreads();

  for (int s = 0; s < TT; ++s) {
    // waits: own h(s-1); layer-1 waits input h0(s); layer-0 throttled by ring depth
    if (tid == 0 && s > 0)      { if (!spinf(&flags[g*1024 + s-1], abortf)) sab = 1; }
    if (tid == 64 && l == 1)    { if (!spinf(&flags[d*1024 + s], abortf)) sab = 1; }
    if (tid == 128 && l == 0 && s >= 15) { if (!spinf(&flags[(2+d)*1024 + s-15], abortf)) sab = 1; }
    __syncthreads();
    if (sab) return;

    // ---- stage X (bf16) and Hprev (hi+lo bf16) into LDS ----
    const int t_time = d ? (TT-1-s) : s;
    const float* xsrc; size_t xstride;
    if (l == 0) { xsrc = x + (size_t)t_time*DD; xstride = (size_t)TT*DD; }
    else        { xsrc = Hin + ((size_t)((s+1)&(RING-1))*BB)*HH; xstride = HH; }
    const int own_rd = (l==0) ? (s & (RING-1)) : s;
    const float* hsrc = Hown + ((size_t)own_rd*BB)*HH;
#pragma unroll
    for (int rr = 0; rr < 8; ++rr) {
      int row = q*8 + rr;
      const float* px = xsrc + (size_t)row*xstride + (size_t)lane*8;
      float4 xa = *(const float4*)px;
      float4 xb4 = *(const float4*)(px + 4);
      bf16x8 xv = { (bf16)xa.x,(bf16)xa.y,(bf16)xa.z,(bf16)xa.w,
                    (bf16)xb4.x,(bf16)xb4.y,(bf16)xb4.z,(bf16)xb4.w };
      *(bf16x8*)(sXs + SWZ(row, lane*16)) = xv;

      const float* ph = hsrc + (size_t)row*HH + (size_t)lane*8;
      float4 ha = *(const float4*)ph;
      float4 hb4 = *(const float4*)(ph + 4);
      float hf[8] = {ha.x,ha.y,ha.z,ha.w,hb4.x,hb4.y,hb4.z,hb4.w};
      bf16x8 hv, lv;
#pragma unroll
      for (int e = 0; e < 8; ++e) {
        bf16 hi = (bf16)hf[e];
        hv[e] = hi;
        lv[e] = (bf16)(hf[e] - (float)hi);
      }
      *(bf16x8*)(sHhi + SWZ(row, lane*16)) = hv;
      *(bf16x8*)(sHlo + SWZ(row, lane*16)) = lv;
    }
    __syncthreads();

    // ---- MFMA: gates = X@Wi (bf16) + Hprev@Wh (split hi/lo, 3 terms) ----
    f32x4 acc = {0.f, 0.f, 0.f, 0.f};
    const int arow = mt*16 + (lane & 15);
    const u32 ab = (u32)kr0 * 2u;
#pragma unroll
    for (int ks = 0; ks < 16; ++ks) {
      bf16x8 a = *(const bf16x8*)(sXs + SWZ(arow, (u32)ks*64u + ab));
      acc = __builtin_amdgcn_mfma_f32_16x16x32_bf16(a, BWi[ks], acc, 0, 0, 0);
    }
#pragma unroll
    for (int ks = 0; ks < 16; ++ks) {
      bf16x8 ahi = *(const bf16x8*)(sHhi + SWZ(arow, (u32)ks*64u + ab));
      bf16x8 alo = *(const bf16x8*)(sHlo + SWZ(arow, (u32)ks*64u + ab));
      bf16x8 wlo = *(const bf16x8*)(sWhlo + (u32)nt*16384u + (u32)ks*1024u + (u32)lane*16u);
      acc = __builtin_amdgcn_mfma_f32_16x16x32_bf16(ahi, BWh[ks], acc, 0, 0, 0);
      acc = __builtin_amdgcn_mfma_f32_16x16x32_bf16(alo, BWh[ks], acc, 0, 0, 0);
      acc = __builtin_amdgcn_mfma_f32_16x16x32_bf16(ahi, wlo, acc, 0, 0, 0);
    }

    // ---- gate exchange via LDS: D row = batch = 4*(lane>>4)+r, col = c_loc ----
#pragma unroll
    for (int r = 0; r < 4; ++r) {
      int brow = mt*16 + (lane >> 4)*4 + r;
      gatebuf[brow*32 + c_loc] = acc[r];
    }
    __syncthreads();

    float gi = gatebuf[bthr*32 + uthr*4 + 0] + bgi;
    float gf = gatebuf[bthr*32 + uthr*4 + 1] + bgf;
    float gg = gatebuf[bthr*32 + uthr*4 + 2] + bgg;
    float go = gatebuf[bthr*32 + uthr*4 + 3] + bgo;
    float si = 1.f/(1.f + __expf(-gi));
    float sf = 1.f/(1.f + __expf(-gf));
    float so = 1.f/(1.f + __expf(-go));
    cst = sf*cst + si*tanhf(gg);
    float h = so*tanhf(cst);
    const int own_wr = (l==0) ? ((s+1) & (RING-1)) : (s+1);
    Hown[((size_t)own_wr*BB + bthr)*HH + hu] = h;
    __threadfence();
    __syncthreads();
    if (tid == 0) atomicAdd(&flags[g*1024 + s], 1);
  }
}

__launch_bounds__(256, 2)
__global__ void k_out(const unsigned char* __restrict__ ws,
                      const float* __restrict__ bout,
                      float* __restrict__ out) {
  __shared__ unsigned char As[64*128];    // [64 m][64 k] bf16 swizzled
  __shared__ unsigned char Bs[128*128];   // [128 j][64 k] bf16 swizzled (W_out^T)
  const float* Hf = (const float*)(ws + OFF_H1);
  const float* Hb = Hf + FULL_ELEM;
  const bf16* wbt = (const bf16*)(ws + OFF_WBT);

  const int m0 = blockIdx.x * 64;
  const int j0 = blockIdx.y * 128;
  const int tid = threadIdx.x, lane = tid & 63, q = tid >> 6;
  const int b = m0 >> 10;           // uniform per block (T=1024 divides tiles)
  const int t0 = m0 & 1023;

  f32x4 acc[2][4];
#pragma unroll
  for (int mi = 0; mi < 2; ++mi)
#pragma unroll
    for (int ni = 0; ni < 4; ++ni) acc[mi][ni] = (f32x4){0.f,0.f,0.f,0.f};

  for (int kb = 0; kb < 16; ++kb) {
#pragma unroll
    for (int it = 0; it < 2; ++it) {
      int row = tid >> 2;
      int chunk = (tid & 3) + it*4;
      int k0 = kb*64 + chunk*8;
      int t = t0 + row;
      const float* src = (k0 < 512)
        ? (Hf + ((size_t)(t+1)*BB + b)*HH + k0)
        : (Hb + ((size_t)(TT-t)*BB + b)*HH + (k0-512));
      float4 fa = *(const float4*)src;
      float4 fb = *(const float4*)(src + 4);
      bf16x8 v = { (bf16)fmaxf(fa.x,0.f),(bf16)fmaxf(fa.y,0.f),(bf16)fmaxf(fa.z,0.f),(bf16)fmaxf(fa.w,0.f),
                   (bf16)fmaxf(fb.x,0.f),(bf16)fmaxf(fb.y,0.f),(bf16)fmaxf(fb.z,0.f),(bf16)fmaxf(fb.w,0.f) };
      *(bf16x8*)(As + SWZG(row, chunk*16)) = v;
    }
#pragma unroll
    for (int it = 0; it < 4; ++it) {
      int j = (tid >> 3) + it*32;
      int chunk = tid & 7;
      int k0 = kb*64 + chunk*8;
      bf16x8 v = *(const bf16x8*)(wbt + (size_t)(j0+j)*1024 + k0);
      *(bf16x8*)(Bs + SWZG(j, chunk*16)) = v;
    }
    __syncthreads();
    const int mrow = (q & 1)*32;
    const int nc0 = (q >> 1)*64;
#pragma unroll
    for (int ks = 0; ks < 2; ++ks) {
      u32 koff = (u32)(ks*32 + (lane>>4)*8) * 2u;
      bf16x8 afr[2];
#pragma unroll
      for (int mi = 0; mi < 2; ++mi)
        afr[mi] = *(const bf16x8*)(As + SWZG(mrow + mi*16 + (lane&15), koff));
#pragma unroll
      for (int ni = 0; ni < 4; ++ni) {
        bf16x8 bfr = *(const bf16x8*)(Bs + SWZG(nc0 + ni*16 + (lane&15), koff));
#pragma unroll
        for (int mi = 0; mi < 2; ++mi)
          acc[mi][ni] = __builtin_amdgcn_mfma_f32_16x16x32_bf16(afr[mi], bfr, acc[mi][ni], 0, 0, 0);
      }
    }
    __syncthreads();
  }
#pragma unroll
  for (int ni = 0; ni < 4; ++ni) {
    int col = j0 + (q >> 1)*64 + ni*16 + (lane & 15);
    float bv = bout[col];
#pragma unroll
    for (int mi = 0; mi < 2; ++mi) {
#pragma unroll
      for (int r = 0; r < 4; ++r) {
        int m = m0 + (q & 1)*32 + mi*16 + (lane >> 4)*4 + r;
        out[(size_t)m*1024 + col] = acc[mi][ni][r] + bv;
      }
    }
  }
}

extern "C" void kernel_launch(void* const* d_in, const int* in_sizes, int n_in,
                              void* d_out, int out_size, void* d_ws, size_t ws_size,
                              hipStream_t stream) {
  const float* x    = (const float*)d_in[0];
  const float* h0   = (const float*)d_in[1];
  const float* c0   = (const float*)d_in[2];
  const float* Wi_f = (const float*)d_in[3];
  const float* Wh_f = (const float*)d_in[4];
  const float* b_f  = (const float*)d_in[5];
  const float* Wi_b = (const float*)d_in[6];
  const float* Wh_b = (const float*)d_in[7];
  const float* b_b  = (const float*)d_in[8];
  const float* Wo   = (const float*)d_in[9];
  const float* bo   = (const float*)d_in[10];
  unsigned char* ws = (unsigned char*)d_ws;
  float* out = (float*)d_out;

  hipLaunchKernelGGL(k_setup, dim3(256), dim3(256), 0, stream, h0, Wo, ws);

  void* args[] = { (void*)&x, (void*)&c0, (void*)&Wi_f, (void*)&Wh_f, (void*)&b_f,
                   (void*)&Wi_b, (void*)&Wh_b, (void*)&b_b, (void*)&ws };
  hipError_t e = hipLaunchCooperativeKernel((const void*)k_rnn, dim3(256), dim3(256),
                                            args, 0, stream);
  if (e != hipSuccess) {
    // all 256 wgs (<=1 per CU) are trivially co-resident; normal launch is a safe fallback
    hipLaunchKernelGGL(k_rnn, dim3(256), dim3(256), 0, stream,
                       x, c0, Wi_f, Wh_f, b_f, Wi_b, Wh_b, b_b, ws);
  }

  hipLaunchKernelGGL(k_out, dim3(512, 8), dim3(256), 0, stream,
                     (const unsigned char*)ws, bo, out);
}

// Round 2
// 6435.025 us; speedup vs baseline: 5.9442x; 5.9442x over previous
//
#include <hip/hip_runtime.h>
#include <math.h>

typedef __bf16 bf16;
typedef __bf16 bf16x8 __attribute__((ext_vector_type(8)));
typedef float f32x4 __attribute__((ext_vector_type(4)));
typedef int i32x4 __attribute__((ext_vector_type(4)));
typedef unsigned int u32;

#define TT 1024
#define BB 32
#define DD 512
#define HH 512
#define NG4 2048

// ---- workspace layout (bytes) ----
#define OFF_FLAGS 0ull
#define FLAG_INTS (4u*1024u*64u)                 // fown[g][s][w]
#define OFF_ABORT ((size_t)FLAG_INTS*4ull)       // 1 MB
#define OFF_WBT   (OFF_ABORT + 1024ull)
#define OFF_PL    (OFF_WBT + 2097152ull)         // hi/lo bf16 plane rings
#define PL_BYTES  32768ull                       // one slot: 32*512*2B
#define OFF_H1    (OFF_PL + 4ull*2ull*16ull*PL_BYTES)
#define FULL_ELEM ((size_t)(TT+1)*BB*HH)         // fp32 H1 per dir

#define PLP(gg, pp, slot) (ws + OFF_PL + (((size_t)((gg)*2+(pp))*16 + (size_t)(slot))*PL_BYTES))

// IF$-coherent (cache-bypassing) accessors: sc0 sc1 = bypass L1+L2, data
// lives at the device coherence point, so no wbl2/inv fences are needed.
__device__ __forceinline__ bf16x8 load16_sc(const void* p) {
  i32x4 r;
  asm volatile("global_load_dwordx4 %0, %1, off sc0 sc1" : "=v"(r) : "v"(p) : "memory");
  return __builtin_bit_cast(bf16x8, r);
}
__device__ __forceinline__ void store_short_sc(void* p, u32 v) {
  asm volatile("global_store_short %0, %1, off sc0 sc1" :: "v"(p), "v"(v) : "memory");
}

__device__ __forceinline__ bool pollrow(int* row, int lane, int* abortf) {
  int it = 0;
  while (true) {
    int v = __hip_atomic_load(row + lane, __ATOMIC_RELAXED, __HIP_MEMORY_SCOPE_AGENT);
    if (__all(v != 0)) return true;
    __builtin_amdgcn_s_sleep(1);
    if ((++it & 1023) == 0) {
      if (it > (1 << 21)) {
        __hip_atomic_store(abortf, 1, __ATOMIC_RELAXED, __HIP_MEMORY_SCOPE_AGENT);
        return false;
      }
      if (__hip_atomic_load(abortf, __ATOMIC_RELAXED, __HIP_MEMORY_SCOPE_AGENT)) return false;
    }
  }
}

__global__ void k_setup(const float* __restrict__ h0,
                        const float* __restrict__ wout,
                        unsigned char* __restrict__ ws) {
  bf16* wbt  = (bf16*)(ws + OFF_WBT);
  int* flags = (int*)(ws + OFF_FLAGS);
  const u32 wcnt = 1024u*1024u;
  const u32 pcnt = 4u*BB*HH;
  const u32 fcnt = FLAG_INTS + 1u;             // + abort word
  const u32 total = wcnt + pcnt + fcnt;
  for (u32 i = blockIdx.x*blockDim.x + threadIdx.x; i < total; i += gridDim.x*blockDim.x) {
    if (i < wcnt) {
      u32 j = i >> 10, k = i & 1023u;
      wbt[(size_t)j*1024u + k] = (bf16)wout[(size_t)k*1024u + j];   // W_out^T
    } else if (i < wcnt + pcnt) {
      u32 t = i - wcnt;
      u32 g = t >> 14;            // layer*2+dir
      u32 rem = t & 16383u;       // b*512+k
      u32 l = g >> 1;
      float v = h0[(size_t)l*(BB*HH) + rem];
      bf16 hi = (bf16)v;
      bf16 lo = (bf16)(v - (float)hi);
      ((bf16*)PLP(g, 0, 15))[rem] = hi;        // slot 15 == h_{-1}
      ((bf16*)PLP(g, 1, 15))[rem] = lo;
    } else {
      flags[i - wcnt - pcnt] = 0;
    }
  }
}

__launch_bounds__(256, 1)
__global__ void k_rnn(const float* __restrict__ x,
                      const float* __restrict__ c0,
                      const float* __restrict__ Wi_f, const float* __restrict__ Wh_f, const float* __restrict__ b_f,
                      const float* __restrict__ Wi_b, const float* __restrict__ Wh_b, const float* __restrict__ b_b,
                      unsigned char* __restrict__ ws) {
  __shared__ float gb[4][32][33];   // per-wave K-partials, padded (+1) for banks
  __shared__ int sab;

  const int bid = blockIdx.x;
  const int g = bid & 3;            // layer*2 + dir (spreads groups across XCDs)
  const int w = bid >> 2;           // owns hidden units w*8..w*8+7
  const int l = g >> 1, d = g & 1;
  const int tid = threadIdx.x;
  const int lane = tid & 63;
  const int q = tid >> 6;           // wave 0..3: owns ks = q*4..q*4+3 (K quarter)

  const float* Wi   = (d ? Wi_b : Wi_f) + (size_t)l*DD*NG4;
  const float* Wh   = (d ? Wh_b : Wh_f) + (size_t)l*HH*NG4;
  const float* bias = (d ? b_b : b_f) + (size_t)l*NG4;

  int* flags  = (int*)(ws + OFF_FLAGS);
  int* abortf = flags + FLAG_INTS;

  const int lrow = lane & 15;          // A row within 16-tile / B col within tile
  const int kr0  = (lane >> 4) * 8;    // k sub-offset within 32-k step

  // ---- one-time: pack Wi / Wh(hi) / Wh(lo) B-fragments for this wave's K quarter ----
  bf16x8 BWi[4][2], BWh[4][2], BWlo[4][2];
#pragma unroll
  for (int j = 0; j < 4; ++j) {
    int k0 = (q*4 + j)*32 + kr0;
#pragma unroll
    for (int nt = 0; nt < 2; ++nt) {
      int cc = nt*16 + lrow;
      int unit = cc >> 2, gate = cc & 3;
      int Jcol = gate*512 + w*8 + unit;
      bf16x8 ai, ah, al;
#pragma unroll
      for (int e = 0; e < 8; ++e) {
        float wi = Wi[(size_t)(k0+e)*NG4 + Jcol];
        float wh = Wh[(size_t)(k0+e)*NG4 + Jcol];
        ai[e] = (bf16)wi;
        bf16 hh = (bf16)wh;
        ah[e] = hh;
        al[e] = (bf16)(wh - (float)hh);
      }
      BWi[j][nt] = ai; BWh[j][nt] = ah; BWlo[j][nt] = al;
    }
  }

  // per-lane byte offsets of A-fragments within a [32][512] bf16 plane
  u32 aoff[4][2];
#pragma unroll
  for (int j = 0; j < 4; ++j)
#pragma unroll
    for (int mt = 0; mt < 2; ++mt)
      aoff[j][mt] = (u32)((((mt*16 + lrow)*512) + (q*4 + j)*32 + kr0) * 2);

  const int bthr = tid >> 3, uthr = tid & 7;
  const int hu = w*8 + uthr;
  float cst = c0[((size_t)l*BB + bthr)*HH + hu];
  const float bgi = bias[hu], bgf = bias[512+hu], bgg = bias[1024+hu], bgo = bias[1536+hu];

  if (tid == 0) sab = 0;
  __syncthreads();

  for (int s = 0; s < TT; ++s) {
    const int slot_w = s & 15;
    const int slot_r = (s + 15) & 15;

    if (l == 1) {
      // gate this step's x-input (layer-0 h at slot_w) — 16 ticks of slack
      if (q == 1) { if (!pollrow(flags + ((size_t)d*1024 + s)*64, lane, abortf)) sab = 1; }
      __syncthreads();                                        // barrier A
    }

    f32x4 acc[2][2];
#pragma unroll
    for (int mt = 0; mt < 2; ++mt)
#pragma unroll
      for (int nt = 0; nt < 2; ++nt) acc[mt][nt] = (f32x4){0.f,0.f,0.f,0.f};

    // ---- x-phase (off own-h critical path; polls overlap load latency) ----
    if (l == 0) {
      const int t_time = d ? (TT-1-s) : s;
      bf16x8 Ax[4][2];
#pragma unroll
      for (int j = 0; j < 4; ++j)
#pragma unroll
        for (int mt = 0; mt < 2; ++mt) {
          const float* px = x + ((size_t)(mt*16 + lrow)*TT + t_time)*DD + (q*4 + j)*32 + kr0;
          float4 a  = *(const float4*)px;
          float4 b4 = *(const float4*)(px + 4);
          bf16x8 v = { (bf16)a.x,(bf16)a.y,(bf16)a.z,(bf16)a.w,
                       (bf16)b4.x,(bf16)b4.y,(bf16)b4.z,(bf16)b4.w };
          Ax[j][mt] = v;
        }
      if (q == 0 && s > 0)   { if (!pollrow(flags + ((size_t)g*1024 + (s-1))*64, lane, abortf)) sab = 1; }
      if (q == 1 && s >= 16) { if (!pollrow(flags + ((size_t)(2+d)*1024 + (s-16))*64, lane, abortf)) sab = 1; }
#pragma unroll
      for (int j = 0; j < 4; ++j)
#pragma unroll
        for (int mt = 0; mt < 2; ++mt)
#pragma unroll
          for (int nt = 0; nt < 2; ++nt)
            acc[mt][nt] = __builtin_amdgcn_mfma_f32_16x16x32_bf16(Ax[j][mt], BWi[j][nt], acc[mt][nt], 0, 0, 0);
    } else {
      const unsigned char* xb = PLP(d, 0, slot_w);
      bf16x8 Ax[4][2];
#pragma unroll
      for (int j = 0; j < 4; ++j)
#pragma unroll
        for (int mt = 0; mt < 2; ++mt)
          Ax[j][mt] = load16_sc(xb + aoff[j][mt]);
      if (q == 0 && s > 0) { if (!pollrow(flags + ((size_t)g*1024 + (s-1))*64, lane, abortf)) sab = 1; }
      asm volatile("s_waitcnt vmcnt(0)" ::: "memory");
      __builtin_amdgcn_sched_barrier(0);
#pragma unroll
      for (int j = 0; j < 4; ++j)
#pragma unroll
        for (int mt = 0; mt < 2; ++mt)
#pragma unroll
          for (int nt = 0; nt < 2; ++nt)
            acc[mt][nt] = __builtin_amdgcn_mfma_f32_16x16x32_bf16(Ax[j][mt], BWi[j][nt], acc[mt][nt], 0, 0, 0);
    }
    __syncthreads();                                          // barrier B
    if (sab) return;

    // ---- h-phase: direct-to-register split-precision fragments ----
    const unsigned char* hb = PLP(g, 0, slot_r);
    const unsigned char* lb = PLP(g, 1, slot_r);
    bf16x8 Ahi[4][2], Alo[4][2];
#pragma unroll
    for (int j = 0; j < 4; ++j)
#pragma unroll
      for (int mt = 0; mt < 2; ++mt) {
        Ahi[j][mt] = load16_sc(hb + aoff[j][mt]);
        Alo[j][mt] = load16_sc(lb + aoff[j][mt]);
      }
    asm volatile("s_waitcnt vmcnt(0)" ::: "memory");
    __builtin_amdgcn_sched_barrier(0);
#pragma unroll
    for (int j = 0; j < 4; ++j) {
#pragma unroll
      for (int mt = 0; mt < 2; ++mt)
#pragma unroll
        for (int nt = 0; nt < 2; ++nt)
          acc[mt][nt] = __builtin_amdgcn_mfma_f32_16x16x32_bf16(Ahi[j][mt], BWh[j][nt], acc[mt][nt], 0, 0, 0);
#pragma unroll
      for (int mt = 0; mt < 2; ++mt)
#pragma unroll
        for (int nt = 0; nt < 2; ++nt)
          acc[mt][nt] = __builtin_amdgcn_mfma_f32_16x16x32_bf16(Alo[j][mt], BWh[j][nt], acc[mt][nt], 0, 0, 0);
#pragma unroll
      for (int mt = 0; mt < 2; ++mt)
#pragma unroll
        for (int nt = 0; nt < 2; ++nt)
          acc[mt][nt] = __builtin_amdgcn_mfma_f32_16x16x32_bf16(Ahi[j][mt], BWlo[j][nt], acc[mt][nt], 0, 0, 0);
    }

    // ---- K-reduction + gate exchange through LDS ----
#pragma unroll
    for (int mt = 0; mt < 2; ++mt)
#pragma unroll
      for (int nt = 0; nt < 2; ++nt)
#pragma unroll
        for (int r = 0; r < 4; ++r)
          gb[q][mt*16 + (lane>>4)*4 + r][nt*16 + lrow] = acc[mt][nt][r];
    __syncthreads();                                          // barrier C

    float gi = bgi, gf = bgf, gg2 = bgg, go = bgo;
#pragma unroll
    for (int qq = 0; qq < 4; ++qq) {
      gi  += gb[qq][bthr][uthr*4 + 0];
      gf  += gb[qq][bthr][uthr*4 + 1];
      gg2 += gb[qq][bthr][uthr*4 + 2];
      go  += gb[qq][bthr][uthr*4 + 3];
    }
    float si = 1.f/(1.f + __expf(-gi));
    float sf = 1.f/(1.f + __expf(-gf));
    float so = 1.f/(1.f + __expf(-go));
    cst = sf*cst + si*tanhf(gg2);
    float h = so*tanhf(cst);

    bf16 hh = (bf16)h;
    bf16 hl = (bf16)(h - (float)hh);
    u32 off2 = (u32)((bthr*512 + hu) * 2);
    store_short_sc((void*)(PLP(g, 0, slot_w) + off2), (u32)__builtin_bit_cast(unsigned short, hh));
    store_short_sc((void*)(PLP(g, 1, slot_w) + off2), (u32)__builtin_bit_cast(unsigned short, hl));
    if (l == 1) {
      float* H1 = (float*)(ws + OFF_H1) + (size_t)d*FULL_ELEM;
      H1[((size_t)(s+1)*BB + bthr)*HH + hu] = h;             // plain store, read post-kernel
    }
    asm volatile("s_waitcnt vmcnt(0)" ::: "memory");          // drain write-through stores
    __syncthreads();                                          // barrier D
    if (tid == 0)
      __hip_atomic_store(flags + ((size_t)g*1024 + s)*64 + w, 1,
                         __ATOMIC_RELAXED, __HIP_MEMORY_SCOPE_AGENT);
  }
}

#define SWZG(row, bc) ((u32)(row)*128u + ((u32)(bc) ^ ((((u32)(row))&7u)<<4)))

__launch_bounds__(256, 2)
__global__ void k_out(const unsigned char* __restrict__ ws,
                      const float* __restrict__ bout,
                      float* __restrict__ out) {
  __shared__ unsigned char As[64*128];
  __shared__ unsigned char Bs[128*128];
  const float* Hf = (const float*)(ws + OFF_H1);
  const float* Hb = Hf + FULL_ELEM;
  const bf16* wbt = (const bf16*)(ws + OFF_WBT);

  const int m0 = blockIdx.x * 64;
  const int j0 = blockIdx.y * 128;
  const int tid = threadIdx.x, lane = tid & 63, q = tid >> 6;
  const int b = m0 >> 10;
  const int t0 = m0 & 1023;

  f32x4 acc[2][4];
#pragma unroll
  for (int mi = 0; mi < 2; ++mi)
#pragma unroll
    for (int ni = 0; ni < 4; ++ni) acc[mi][ni] = (f32x4){0.f,0.f,0.f,0.f};

  for (int kb = 0; kb < 16; ++kb) {
#pragma unroll
    for (int it = 0; it < 2; ++it) {
      int row = tid >> 2;
      int chunk = (tid & 3) + it*4;
      int k0 = kb*64 + chunk*8;
      int t = t0 + row;
      const float* src = (k0 < 512)
        ? (Hf + ((size_t)(t+1)*BB + b)*HH + k0)
        : (Hb + ((size_t)(TT-t)*BB + b)*HH + (k0-512));
      float4 fa = *(const float4*)src;
      float4 fb = *(const float4*)(src + 4);
      bf16x8 v = { (bf16)fmaxf(fa.x,0.f),(bf16)fmaxf(fa.y,0.f),(bf16)fmaxf(fa.z,0.f),(bf16)fmaxf(fa.w,0.f),
                   (bf16)fmaxf(fb.x,0.f),(bf16)fmaxf(fb.y,0.f),(bf16)fmaxf(fb.z,0.f),(bf16)fmaxf(fb.w,0.f) };
      *(bf16x8*)(As + SWZG(row, chunk*16)) = v;
    }
#pragma unroll
    for (int it = 0; it < 4; ++it) {
      int j = (tid >> 3) + it*32;
      int chunk = tid & 7;
      int k0 = kb*64 + chunk*8;
      bf16x8 v = *(const bf16x8*)(wbt + (size_t)(j0+j)*1024 + k0);
      *(bf16x8*)(Bs + SWZG(j, chunk*16)) = v;
    }
    __syncthreads();
    const int mrow = (q & 1)*32;
    const int nc0 = (q >> 1)*64;
#pragma unroll
    for (int ks = 0; ks < 2; ++ks) {
      u32 koff = (u32)(ks*32 + (lane>>4)*8) * 2u;
      bf16x8 afr[2];
#pragma unroll
      for (int mi = 0; mi < 2; ++mi)
        afr[mi] = *(const bf16x8*)(As + SWZG(mrow + mi*16 + (lane&15), koff));
#pragma unroll
      for (int ni = 0; ni < 4; ++ni) {
        bf16x8 bfr = *(const bf16x8*)(Bs + SWZG(nc0 + ni*16 + (lane&15), koff));
#pragma unroll
        for (int mi = 0; mi < 2; ++mi)
          acc[mi][ni] = __builtin_amdgcn_mfma_f32_16x16x32_bf16(afr[mi], bfr, acc[mi][ni], 0, 0, 0);
      }
    }
    __syncthreads();
  }
#pragma unroll
  for (int ni = 0; ni < 4; ++ni) {
    int col = j0 + (q >> 1)*64 + ni*16 + (lane & 15);
    float bv = bout[col];
#pragma unroll
    for (int mi = 0; mi < 2; ++mi) {
#pragma unroll
      for (int r = 0; r < 4; ++r) {
        int m = m0 + (q & 1)*32 + mi*16 + (lane >> 4)*4 + r;
        out[(size_t)m*1024 + col] = acc[mi][ni][r] + bv;
      }
    }
  }
}

extern "C" void kernel_launch(void* const* d_in, const int* in_sizes, int n_in,
                              void* d_out, int out_size, void* d_ws, size_t ws_size,
                              hipStream_t stream) {
  const float* x    = (const float*)d_in[0];
  const float* h0   = (const float*)d_in[1];
  const float* c0   = (const float*)d_in[2];
  const float* Wi_f = (const float*)d_in[3];
  const float* Wh_f = (const float*)d_in[4];
  const float* b_f  = (const float*)d_in[5];
  const float* Wi_b = (const float*)d_in[6];
  const float* Wh_b = (const float*)d_in[7];
  const float* b_b  = (const float*)d_in[8];
  const float* Wo   = (const float*)d_in[9];
  const float* bo   = (const float*)d_in[10];
  unsigned char* ws = (unsigned char*)d_ws;
  float* out = (float*)d_out;

  hipLaunchKernelGGL(k_setup, dim3(256), dim3(256), 0, stream, h0, Wo, ws);

  void* args[] = { (void*)&x, (void*)&c0, (void*)&Wi_f, (void*)&Wh_f, (void*)&b_f,
                   (void*)&Wi_b, (void*)&Wh_b, (void*)&b_b, (void*)&ws };
  hipError_t e = hipLaunchCooperativeKernel((const void*)k_rnn, dim3(256), dim3(256),
                                            args, 0, stream);
  if (e != hipSuccess) {
    hipLaunchKernelGGL(k_rnn, dim3(256), dim3(256), 0, stream,
                       x, c0, Wi_f, Wh_f, b_f, Wi_b, Wh_b, b_b, ws);
  }

  hipLaunchKernelGGL(k_out, dim3(512, 8), dim3(256), 0, stream,
                     (const unsigned char*)ws, bo, out);
}